// Round 9
// baseline (69.252 us; speedup 1.0000x reference)
//
#include <hip/hip_runtime.h>
#include <hip/hip_bf16.h>

// JointLengthLoss: mean over [B,20] of | ||pred_a-pred_b|| - ||gt_a-gt_b|| | / ||gt_a-gt_b||
// B = 524288, joints [B,21,3] f32.
//
// R8 = R7 (global_load_lds staging, double-buffered, counted vmcnt;
// wave-per-bone-group compute -> 0 bank conflicts) + micro:
//  - peeled last iteration (branch-free hot loop)
//  - sched_barrier removed (consumers are memory ops, ordered by "memory" clobber)
//  - NBLOCKS=256 (32 tiles/block), single-wave finalize (no LDS/syncthreads)

#define TILE_BYTES   16128          // 64 samples * 63 floats * 4B
#define TILE_PAD_F   4096           // 16384 B per input per buffer (256B pad for clamped tail)
#define NBLOCKS      256

// 7-joint lists per bone group; edges are ALWAYS (0,1),(2,3),(3,4),(4,5),(5,6).
// g0: (3,2),(2,20),(20,8),(8,9),(9,10)       g1: (10,11),(20,4),(4,5),(5,6),(6,7)
// g2: (20,1),(1,0),(0,16),(16,17),(17,18)    g3: (18,19),(0,12),(12,13),(13,14),(14,15)
static constexpr int JT0[7] = {3,2,2,20,8,9,10};
static constexpr int JT1[7] = {10,11,20,4,5,6,7};
static constexpr int JT2[7] = {20,1,1,0,16,17,18};
static constexpr int JT3[7] = {18,19,0,12,13,14,15};
static constexpr int EA[5] = {0,2,3,4,5};
static constexpr int EB[5] = {1,3,4,5,6};

typedef __attribute__((address_space(1))) const void gvoid_t;
typedef __attribute__((address_space(3))) void lvoid_t;

template<int G>
__device__ __forceinline__ float bone_group(const float* __restrict__ SP,
                                            const float* __restrict__ SG) {
    float px[7], py[7], pz[7], qx[7], qy[7], qz[7];
    #pragma unroll
    for (int k = 0; k < 7; ++k) {
        const int o = 3 * ((G == 0) ? JT0[k] : (G == 1) ? JT1[k] : (G == 2) ? JT2[k] : JT3[k]);
        px[k] = SP[o + 0]; py[k] = SP[o + 1]; pz[k] = SP[o + 2];
        qx[k] = SG[o + 0]; qy[k] = SG[o + 1]; qz[k] = SG[o + 2];
    }
    float s = 0.0f;
    #pragma unroll
    for (int e = 0; e < 5; ++e) {
        const int a = EA[e], b = EB[e];
        float dx = px[a] - px[b];
        float dy = py[a] - py[b];
        float dz = pz[a] - pz[b];
        float pl = sqrtf(dx * dx + dy * dy + dz * dz);
        float ex = qx[a] - qx[b];
        float ey = qy[a] - qy[b];
        float ez = qz[a] - qz[b];
        float gl = sqrtf(ex * ex + ey * ey + ez * ez);
        s += fabsf(pl - gl) / gl;
    }
    return s;
}

__global__ __launch_bounds__(256)
void jll_kernel(const float* __restrict__ pred,
                const float* __restrict__ gt,
                float* __restrict__ partials,
                int tiles_per_block) {
    __shared__ __align__(16) float lds[2][2][TILE_PAD_F];   // [buf][input][floats] = 64 KiB
    __shared__ float wsum[4];

    const int tid  = threadIdx.x;
    const int wave = tid >> 6;
    const int lane = tid & 63;

    const size_t tile0 = (size_t)blockIdx.x * tiles_per_block;

    // STAGE: 8 global_load_lds per thread (4 chunks x {pred,gt}).
    // LDS dest: wave-uniform base + lane*16 (HW rule). Global src: per-lane.
    // Tail chunk 15: lanes >=48 clamp to the last valid 16B of the tile;
    // their LDS writes land in the 256B pad (floats 4032..4095, never read).
    auto STAGE = [&](int q, size_t tile) {
        const char* srcP = (const char*)pred + tile * (size_t)TILE_BYTES;
        const char* srcG = (const char*)gt   + tile * (size_t)TILE_BYTES;
        #pragma unroll
        for (int c = 0; c < 4; ++c) {
            const int chunk = wave * 4 + c;
            int off = chunk * 1024 + lane * 16;
            if (off > TILE_BYTES - 16) off = TILE_BYTES - 16;
            __builtin_amdgcn_global_load_lds(
                (gvoid_t*)(srcP + off), (lvoid_t*)&lds[q][0][chunk * 256], 16, 0, 0);
            __builtin_amdgcn_global_load_lds(
                (gvoid_t*)(srcG + off), (lvoid_t*)&lds[q][1][chunk * 256], 16, 0, 0);
        }
    };

    auto COMPUTE = [&](int q) -> float {
        const float* SP = &lds[q][0][lane * 63];
        const float* SG = &lds[q][1][lane * 63];
        float ts;
        if      (wave == 0) ts = bone_group<0>(SP, SG);
        else if (wave == 1) ts = bone_group<1>(SP, SG);
        else if (wave == 2) ts = bone_group<2>(SP, SG);
        else                ts = bone_group<3>(SP, SG);
        return ts;
    };

    float sum = 0.0f;

    STAGE(0, tile0);                               // prologue: tile 0 -> buf 0 (8 in flight)

    // hot loop: branch-free (last iteration peeled)
    for (int t = 0; t < tiles_per_block - 1; ++t) {
        STAGE((t + 1) & 1, tile0 + t + 1);         // 8 more in flight (16 total)
        // retire tile t's 8 loads; keep tile t+1's 8 in flight across the barrier
        asm volatile("s_waitcnt vmcnt(8)\n\ts_barrier" ::: "memory");

        sum += COMPUTE(t & 1);

        // all waves done reading buf[t&1] before iter t+1 issues STAGE into it
        asm volatile("s_waitcnt lgkmcnt(0)\n\ts_barrier" ::: "memory");
    }

    // epilogue: last tile
    asm volatile("s_waitcnt vmcnt(0)\n\ts_barrier" ::: "memory");
    sum += COMPUTE((tiles_per_block - 1) & 1);

    // ---- wave64 shuffle reduction, then cross-wave via LDS ----
    #pragma unroll
    for (int off = 32; off > 0; off >>= 1)
        sum += __shfl_down(sum, off);

    if (lane == 0) wsum[wave] = sum;
    __syncthreads();
    if (tid == 0)
        partials[blockIdx.x] = wsum[0] + wsum[1] + wsum[2] + wsum[3];
}

__global__ __launch_bounds__(64)
void jll_final_kernel(const float* __restrict__ partials, int nparts,
                      float* __restrict__ out, float inv_count) {
    const int lane = threadIdx.x;        // single wave, no LDS, no syncthreads
    float sum = 0.0f;
    for (int i = lane; i < nparts; i += 64) sum += partials[i];

    #pragma unroll
    for (int off = 32; off > 0; off >>= 1)
        sum += __shfl_down(sum, off);

    if (lane == 0)
        out[0] = sum * inv_count;
}

extern "C" void kernel_launch(void* const* d_in, const int* in_sizes, int n_in,
                              void* d_out, int out_size, void* d_ws, size_t ws_size,
                              hipStream_t stream) {
    const float* pred = (const float*)d_in[0];
    const float* gt   = (const float*)d_in[1];
    float* out = (float*)d_out;
    float* partials = (float*)d_ws;

    const int nsamples = in_sizes[0] / 63;            // 524288
    const int ntiles   = nsamples / 64;               // 8192
    const int tiles_per_block = ntiles / NBLOCKS;     // 32 (exact)

    jll_kernel<<<NBLOCKS, 256, 0, stream>>>(pred, gt, partials, tiles_per_block);

    const float inv_count = 1.0f / ((float)nsamples * 20.0f);
    jll_final_kernel<<<1, 64, 0, stream>>>(partials, NBLOCKS, out, inv_count);
}

// Round 10
// 49.381 us; speedup vs baseline: 1.4024x; 1.4024x over previous
//
#include <hip/hip_runtime.h>
#include <hip/hip_bf16.h>

// JointLengthLoss: mean over [B,20] of | ||pred_a-pred_b|| - ||gt_a-gt_b|| | / ||gt_a-gt_b||
// B = 524288, joints [B,21,3] f32.
//
// R9 = R7 grid (NBLOCKS=512 -> 2 blocks/CU resident; R8's 256 halved occupancy
// to 1 block/CU and cost +22us) + R8's neutral micro-opts:
//  - peeled last iteration (branch-free hot loop)
//  - single-wave finalize (no LDS/syncthreads)
// Structure: global_load_lds staging, double-buffered, counted vmcnt(8);
// wave-per-bone-group compute (wave-uniform joint offsets, lane=sample,
// stride 63 -> 2 lanes/bank = conflict-free; SQ_LDS_BANK_CONFLICT == 0).

#define TILE_BYTES   16128          // 64 samples * 63 floats * 4B
#define TILE_PAD_F   4096           // 16384 B per input per buffer (256B pad for clamped tail)
#define NBLOCKS      512

// 7-joint lists per bone group; edges are ALWAYS (0,1),(2,3),(3,4),(4,5),(5,6).
// g0: (3,2),(2,20),(20,8),(8,9),(9,10)       g1: (10,11),(20,4),(4,5),(5,6),(6,7)
// g2: (20,1),(1,0),(0,16),(16,17),(17,18)    g3: (18,19),(0,12),(12,13),(13,14),(14,15)
static constexpr int JT0[7] = {3,2,2,20,8,9,10};
static constexpr int JT1[7] = {10,11,20,4,5,6,7};
static constexpr int JT2[7] = {20,1,1,0,16,17,18};
static constexpr int JT3[7] = {18,19,0,12,13,14,15};
static constexpr int EA[5] = {0,2,3,4,5};
static constexpr int EB[5] = {1,3,4,5,6};

typedef __attribute__((address_space(1))) const void gvoid_t;
typedef __attribute__((address_space(3))) void lvoid_t;

template<int G>
__device__ __forceinline__ float bone_group(const float* __restrict__ SP,
                                            const float* __restrict__ SG) {
    float px[7], py[7], pz[7], qx[7], qy[7], qz[7];
    #pragma unroll
    for (int k = 0; k < 7; ++k) {
        const int o = 3 * ((G == 0) ? JT0[k] : (G == 1) ? JT1[k] : (G == 2) ? JT2[k] : JT3[k]);
        px[k] = SP[o + 0]; py[k] = SP[o + 1]; pz[k] = SP[o + 2];
        qx[k] = SG[o + 0]; qy[k] = SG[o + 1]; qz[k] = SG[o + 2];
    }
    float s = 0.0f;
    #pragma unroll
    for (int e = 0; e < 5; ++e) {
        const int a = EA[e], b = EB[e];
        float dx = px[a] - px[b];
        float dy = py[a] - py[b];
        float dz = pz[a] - pz[b];
        float pl = sqrtf(dx * dx + dy * dy + dz * dz);
        float ex = qx[a] - qx[b];
        float ey = qy[a] - qy[b];
        float ez = qz[a] - qz[b];
        float gl = sqrtf(ex * ex + ey * ey + ez * ez);
        s += fabsf(pl - gl) / gl;
    }
    return s;
}

__global__ __launch_bounds__(256)
void jll_kernel(const float* __restrict__ pred,
                const float* __restrict__ gt,
                float* __restrict__ partials,
                int tiles_per_block) {
    __shared__ __align__(16) float lds[2][2][TILE_PAD_F];   // [buf][input][floats] = 64 KiB
    __shared__ float wsum[4];

    const int tid  = threadIdx.x;
    const int wave = tid >> 6;
    const int lane = tid & 63;

    const size_t tile0 = (size_t)blockIdx.x * tiles_per_block;

    // STAGE: 8 global_load_lds per thread (4 chunks x {pred,gt}).
    // LDS dest: wave-uniform base + lane*16 (HW rule). Global src: per-lane.
    // Tail chunk 15: lanes >=48 clamp to the last valid 16B of the tile;
    // their LDS writes land in the 256B pad (floats 4032..4095, never read).
    auto STAGE = [&](int q, size_t tile) {
        const char* srcP = (const char*)pred + tile * (size_t)TILE_BYTES;
        const char* srcG = (const char*)gt   + tile * (size_t)TILE_BYTES;
        #pragma unroll
        for (int c = 0; c < 4; ++c) {
            const int chunk = wave * 4 + c;
            int off = chunk * 1024 + lane * 16;
            if (off > TILE_BYTES - 16) off = TILE_BYTES - 16;
            __builtin_amdgcn_global_load_lds(
                (gvoid_t*)(srcP + off), (lvoid_t*)&lds[q][0][chunk * 256], 16, 0, 0);
            __builtin_amdgcn_global_load_lds(
                (gvoid_t*)(srcG + off), (lvoid_t*)&lds[q][1][chunk * 256], 16, 0, 0);
        }
    };

    auto COMPUTE = [&](int q) -> float {
        const float* SP = &lds[q][0][lane * 63];
        const float* SG = &lds[q][1][lane * 63];
        float ts;
        if      (wave == 0) ts = bone_group<0>(SP, SG);
        else if (wave == 1) ts = bone_group<1>(SP, SG);
        else if (wave == 2) ts = bone_group<2>(SP, SG);
        else                ts = bone_group<3>(SP, SG);
        return ts;
    };

    float sum = 0.0f;

    STAGE(0, tile0);                               // prologue: tile 0 -> buf 0 (8 in flight)

    // hot loop: branch-free (last iteration peeled)
    for (int t = 0; t < tiles_per_block - 1; ++t) {
        STAGE((t + 1) & 1, tile0 + t + 1);         // 8 more in flight (16 total)
        // retire tile t's 8 loads; keep tile t+1's 8 in flight across the barrier
        asm volatile("s_waitcnt vmcnt(8)\n\ts_barrier" ::: "memory");

        sum += COMPUTE(t & 1);

        // all waves done reading buf[t&1] before iter t+1 issues STAGE into it
        asm volatile("s_waitcnt lgkmcnt(0)\n\ts_barrier" ::: "memory");
    }

    // epilogue: last tile
    asm volatile("s_waitcnt vmcnt(0)\n\ts_barrier" ::: "memory");
    sum += COMPUTE((tiles_per_block - 1) & 1);

    // ---- wave64 shuffle reduction, then cross-wave via LDS ----
    #pragma unroll
    for (int off = 32; off > 0; off >>= 1)
        sum += __shfl_down(sum, off);

    if (lane == 0) wsum[wave] = sum;
    __syncthreads();
    if (tid == 0)
        partials[blockIdx.x] = wsum[0] + wsum[1] + wsum[2] + wsum[3];
}

__global__ __launch_bounds__(64)
void jll_final_kernel(const float* __restrict__ partials, int nparts,
                      float* __restrict__ out, float inv_count) {
    const int lane = threadIdx.x;        // single wave, no LDS, no syncthreads
    float sum = 0.0f;
    for (int i = lane; i < nparts; i += 64) sum += partials[i];

    #pragma unroll
    for (int off = 32; off > 0; off >>= 1)
        sum += __shfl_down(sum, off);

    if (lane == 0)
        out[0] = sum * inv_count;
}

extern "C" void kernel_launch(void* const* d_in, const int* in_sizes, int n_in,
                              void* d_out, int out_size, void* d_ws, size_t ws_size,
                              hipStream_t stream) {
    const float* pred = (const float*)d_in[0];
    const float* gt   = (const float*)d_in[1];
    float* out = (float*)d_out;
    float* partials = (float*)d_ws;

    const int nsamples = in_sizes[0] / 63;            // 524288
    const int ntiles   = nsamples / 64;               // 8192
    const int tiles_per_block = ntiles / NBLOCKS;     // 16 (exact)

    jll_kernel<<<NBLOCKS, 256, 0, stream>>>(pred, gt, partials, tiles_per_block);

    const float inv_count = 1.0f / ((float)nsamples * 20.0f);
    jll_final_kernel<<<1, 64, 0, stream>>>(partials, NBLOCKS, out, inv_count);
}

// Round 12
// 47.904 us; speedup vs baseline: 1.4457x; 1.0308x over previous
//
#include <hip/hip_runtime.h>
#include <hip/hip_bf16.h>

// JointLengthLoss: mean over [B,20] of | ||pred_a-pred_b|| - ||gt_a-gt_b|| | / ||gt_a-gt_b||
// B = 524288, joints [B,21,3] f32.
//
// R11 = R7/R10 verbatim (best measured: 47.59 us). R10's bench died to a
// container infra flake (same signature as R4; this exact source passed twice
// before). Final configuration:
// - global_load_lds staging (coalesced, no VGPR round-trip), double-buffered,
//   counted vmcnt(8): next tile's 8 loads stay in flight across the barrier.
// - wave-per-bone-group compute: wave w computes bone group w for all 64
//   samples (lane = sample). Joint offsets are wave-uniform compile-time
//   immediates; LDS banks = (o - lane*63) mod 32 -> 2 lanes/bank = free
//   (SQ_LDS_BANK_CONFLICT == 0 measured).
// - NBLOCKS=512 = 2 blocks/CU resident (64.5 KiB LDS each) so stage/compute
//   phases of the two blocks interleave (R8's 1 block/CU cost +22 us).
// - two-kernel finalize (R6's fused atomicAdd finalize cost +3.5 us).
// Main kernel ~43.5 us for 264 MB read = 6.1 TB/s = 97% of m13 copy ceiling.

#define TILE_BYTES   16128          // 64 samples * 63 floats * 4B
#define TILE_PAD_F   4096           // 16384 B per input per buffer (256B pad for clamped tail)
#define NBLOCKS      512

// 7-joint lists per bone group; edges are ALWAYS (0,1),(2,3),(3,4),(4,5),(5,6).
// g0: (3,2),(2,20),(20,8),(8,9),(9,10)       g1: (10,11),(20,4),(4,5),(5,6),(6,7)
// g2: (20,1),(1,0),(0,16),(16,17),(17,18)    g3: (18,19),(0,12),(12,13),(13,14),(14,15)
static constexpr int JT0[7] = {3,2,2,20,8,9,10};
static constexpr int JT1[7] = {10,11,20,4,5,6,7};
static constexpr int JT2[7] = {20,1,1,0,16,17,18};
static constexpr int JT3[7] = {18,19,0,12,13,14,15};
static constexpr int EA[5] = {0,2,3,4,5};
static constexpr int EB[5] = {1,3,4,5,6};

typedef __attribute__((address_space(1))) const void gvoid_t;
typedef __attribute__((address_space(3))) void lvoid_t;

template<int G>
__device__ __forceinline__ float bone_group(const float* __restrict__ SP,
                                            const float* __restrict__ SG) {
    float px[7], py[7], pz[7], qx[7], qy[7], qz[7];
    #pragma unroll
    for (int k = 0; k < 7; ++k) {
        const int o = 3 * ((G == 0) ? JT0[k] : (G == 1) ? JT1[k] : (G == 2) ? JT2[k] : JT3[k]);
        px[k] = SP[o + 0]; py[k] = SP[o + 1]; pz[k] = SP[o + 2];
        qx[k] = SG[o + 0]; qy[k] = SG[o + 1]; qz[k] = SG[o + 2];
    }
    float s = 0.0f;
    #pragma unroll
    for (int e = 0; e < 5; ++e) {
        const int a = EA[e], b = EB[e];
        float dx = px[a] - px[b];
        float dy = py[a] - py[b];
        float dz = pz[a] - pz[b];
        float pl = sqrtf(dx * dx + dy * dy + dz * dz);
        float ex = qx[a] - qx[b];
        float ey = qy[a] - qy[b];
        float ez = qz[a] - qz[b];
        float gl = sqrtf(ex * ex + ey * ey + ez * ez);
        s += fabsf(pl - gl) / gl;
    }
    return s;
}

__global__ __launch_bounds__(256)
void jll_kernel(const float* __restrict__ pred,
                const float* __restrict__ gt,
                float* __restrict__ partials,
                int tiles_per_block) {
    __shared__ __align__(16) float lds[2][2][TILE_PAD_F];   // [buf][input][floats] = 64 KiB
    __shared__ float wsum[4];

    const int tid  = threadIdx.x;
    const int wave = tid >> 6;
    const int lane = tid & 63;

    const size_t tile0 = (size_t)blockIdx.x * tiles_per_block;

    // STAGE: 8 global_load_lds per thread (4 chunks x {pred,gt}).
    // LDS dest: wave-uniform base + lane*16 (HW rule). Global src: per-lane.
    // Tail chunk 15: lanes >=48 clamp to the last valid 16B of the tile;
    // their LDS writes land in the 256B pad (floats 4032..4095, never read).
    auto STAGE = [&](int q, size_t tile) {
        const char* srcP = (const char*)pred + tile * (size_t)TILE_BYTES;
        const char* srcG = (const char*)gt   + tile * (size_t)TILE_BYTES;
        #pragma unroll
        for (int c = 0; c < 4; ++c) {
            const int chunk = wave * 4 + c;
            int off = chunk * 1024 + lane * 16;
            if (off > TILE_BYTES - 16) off = TILE_BYTES - 16;
            __builtin_amdgcn_global_load_lds(
                (gvoid_t*)(srcP + off), (lvoid_t*)&lds[q][0][chunk * 256], 16, 0, 0);
            __builtin_amdgcn_global_load_lds(
                (gvoid_t*)(srcG + off), (lvoid_t*)&lds[q][1][chunk * 256], 16, 0, 0);
        }
    };

    float sum = 0.0f;

    STAGE(0, tile0);                               // prologue: tile 0 -> buf 0 (8 in flight)

    for (int t = 0; t < tiles_per_block; ++t) {
        if (t + 1 < tiles_per_block) {
            STAGE((t + 1) & 1, tile0 + t + 1);     // 8 more in flight (16 total)
            // retire tile t's 8 loads; keep tile t+1's 8 in flight across the barrier
            asm volatile("s_waitcnt vmcnt(8)\n\ts_barrier" ::: "memory");
        } else {
            asm volatile("s_waitcnt vmcnt(0)\n\ts_barrier" ::: "memory");
        }
        __builtin_amdgcn_sched_barrier(0);         // rule-18 insurance

        // ---- compute tile t: wave w -> bone group w, lane -> sample ----
        {
            const float* SP = &lds[t & 1][0][lane * 63];
            const float* SG = &lds[t & 1][1][lane * 63];
            float ts;
            if      (wave == 0) ts = bone_group<0>(SP, SG);
            else if (wave == 1) ts = bone_group<1>(SP, SG);
            else if (wave == 2) ts = bone_group<2>(SP, SG);
            else                ts = bone_group<3>(SP, SG);
            sum += ts;
        }

        // all waves done reading buf[t&1] before iter t+1 issues STAGE into it
        asm volatile("s_waitcnt lgkmcnt(0)\n\ts_barrier" ::: "memory");
    }

    // ---- wave64 shuffle reduction, then cross-wave via LDS ----
    #pragma unroll
    for (int off = 32; off > 0; off >>= 1)
        sum += __shfl_down(sum, off);

    if (lane == 0) wsum[wave] = sum;
    __syncthreads();
    if (tid == 0)
        partials[blockIdx.x] = wsum[0] + wsum[1] + wsum[2] + wsum[3];
}

__global__ __launch_bounds__(256)
void jll_final_kernel(const float* __restrict__ partials, int nparts,
                      float* __restrict__ out, float inv_count) {
    const int tid = threadIdx.x;
    float sum = 0.0f;
    for (int i = tid; i < nparts; i += 256) sum += partials[i];

    #pragma unroll
    for (int off = 32; off > 0; off >>= 1)
        sum += __shfl_down(sum, off);

    __shared__ float wsum[4];
    const int lane = tid & 63;
    const int wid  = tid >> 6;
    if (lane == 0) wsum[wid] = sum;
    __syncthreads();
    if (tid == 0)
        out[0] = (wsum[0] + wsum[1] + wsum[2] + wsum[3]) * inv_count;
}

extern "C" void kernel_launch(void* const* d_in, const int* in_sizes, int n_in,
                              void* d_out, int out_size, void* d_ws, size_t ws_size,
                              hipStream_t stream) {
    const float* pred = (const float*)d_in[0];
    const float* gt   = (const float*)d_in[1];
    float* out = (float*)d_out;
    float* partials = (float*)d_ws;

    const int nsamples = in_sizes[0] / 63;            // 524288
    const int ntiles   = nsamples / 64;               // 8192
    const int tiles_per_block = ntiles / NBLOCKS;     // 16 (exact)

    jll_kernel<<<NBLOCKS, 256, 0, stream>>>(pred, gt, partials, tiles_per_block);

    const float inv_count = 1.0f / ((float)nsamples * 20.0f);
    jll_final_kernel<<<1, 256, 0, stream>>>(partials, NBLOCKS, out, inv_count);
}